// Round 1
// baseline (218.835 us; speedup 1.0000x reference)
//
#include <hip/hip_runtime.h>
#include <hip/hip_fp16.h>

// GCN 2-layer forward on gfx950 — CSR-gather with fp16 intermediates (fp32
// accumulation), single-kernel bucketed CSR build with 16-padded edge lists
// (dummy node N has all-zero rows), MFMA layer-1 transform.
// R10: k_zs fused into k_gather1 epilogue (h never materializes; after the
// shfl_xor fold ALL 64 lanes hold the aggregated features, so the 64x10 W2
// dot is done in-register across the 4 lane-groups). Saves 25.6MB h traffic
// + one launch; h stays fp32 for the W2 dot (was fp16 round-trip).
// F=128, H=64, O=10. N=100k, E=1.6M.
static constexpr int F = 128;
static constexpr int H = 64;
static constexpr int O = 10;
static constexpr int PSU = 6;          // zs row stride in uints (12 halves, [5]=0 pad)
static constexpr int NBUK_MAX = 256;   // buckets of 512 nodes (dst>>9)
static constexpr int CAP = 12288;      // per-bucket RAW edge capacity (mean 8192, 45σ)
static constexpr int ESCAP = 14336;    // per-bucket PADDED esrc capacity
                                       // (padded mean ~11.7k, σ~180 -> ~14σ headroom)
static constexpr int EPB = 4096;       // edges per block in k_bin
static constexpr int XPAD = 136;       // xh LDS row stride in halves (128 + 8)

typedef _Float16 half8 __attribute__((ext_vector_type(8)));
typedef float floatx4 __attribute__((ext_vector_type(4)));

// block 0: zero bcntg + zero dummy rows (y row N, zs row N);
// blocks 1..32: build W1f = fp16 W1 in MFMA B-fragment order.
__global__ __launch_bounds__(256) void k_init(int* __restrict__ bcntg,
                                              const float* __restrict__ W1,
                                              __half* __restrict__ W1f,
                                              unsigned* __restrict__ yN,
                                              unsigned* __restrict__ zsN) {
    int b = blockIdx.x, t = threadIdx.x;
    if (b == 0) {
        bcntg[t] = 0;
        if (t < 32) yN[t] = 0u;      // y row N: 64 halves
        if (t < PSU) zsN[t] = 0u;    // zs row N
    } else {
        int i = (b - 1) * 256 + t;   // 0..8191
        int j = i & 7, lane = (i >> 3) & 63, sc = i >> 9;
        int s = sc >> 2, c = sc & 3;
        int k = s * 32 + (lane >> 4) * 8 + j;
        int nn = c * 16 + (lane & 15);
        W1f[i] = __float2half(W1[k * H + nn]);
    }
}

// Bin edges by bucket = dst>>9; bucket-contiguous packed 4B entries:
// entry = (dst&511)<<17 | src   (src < 2^17).
__global__ __launch_bounds__(256) void k_bin(const int* __restrict__ src,
                                             const int* __restrict__ dst,
                                             int* __restrict__ bcntg,
                                             unsigned* __restrict__ ebuf, int e_total) {
    __shared__ int hist[NBUK_MAX];
    __shared__ int base[NBUK_MAX];
    __shared__ int loc[NBUK_MAX];
    int t = threadIdx.x;
    hist[t] = 0;
    loc[t] = 0;
    __syncthreads();
    int i0 = blockIdx.x * EPB;
    int i1 = min(i0 + EPB, e_total);
    int i = i0 + 4 * t;
    for (; i + 3 < i1; i += 1024) {
        int4 d4 = *(const int4*)&dst[i];
        atomicAdd(&hist[d4.x >> 9], 1);
        atomicAdd(&hist[d4.y >> 9], 1);
        atomicAdd(&hist[d4.z >> 9], 1);
        atomicAdd(&hist[d4.w >> 9], 1);
    }
    for (; i < i1; ++i) atomicAdd(&hist[dst[i] >> 9], 1);
    __syncthreads();
    if (hist[t] > 0) base[t] = atomicAdd(&bcntg[t], hist[t]);
    __syncthreads();
    i = i0 + 4 * t;
    for (; i + 3 < i1; i += 1024) {
        int4 s4 = *(const int4*)&src[i];
        int4 d4 = *(const int4*)&dst[i];
#pragma unroll
        for (int u = 0; u < 4; ++u) {
            int s = (&s4.x)[u], d = (&d4.x)[u];
            int b = d >> 9;
            int r = base[b] + atomicAdd(&loc[b], 1);
            if (r < CAP)
                ebuf[(size_t)b * CAP + r] = ((unsigned)(d & 511) << 17) | (unsigned)s;
        }
    }
    for (; i < i1; ++i) {
        int s = src[i], d = dst[i];
        int b = d >> 9;
        int r = base[b] + atomicAdd(&loc[b], 1);
        if (r < CAP)
            ebuf[(size_t)b * CAP + r] = ((unsigned)(d & 511) << 17) | (unsigned)s;
    }
}

// One block per bucket: count in-degrees (LDS), LDS-scan 16-padded counts,
// scatter src into bucket-padded esrc (stride ESCAP), pad with dummy node N.
// Emits rowbeg[n] (absolute into esrc), degp[n] (16-padded), dinv[n].
__global__ __launch_bounds__(256) void k_bsort(
    const unsigned* __restrict__ ebuf, const int* __restrict__ bcntg,
    int* __restrict__ rowbeg, int* __restrict__ degp, float* __restrict__ dinv,
    int* __restrict__ esrc, int n_nodes) {
    __shared__ int hc[512];
    __shared__ int sa[512];
    __shared__ int sb[512];
    int t = threadIdx.x, b = blockIdx.x, n0 = b << 9;
    hc[t] = 0;
    hc[t + 256] = 0;
    __syncthreads();
    int cb = min(bcntg[b], CAP);
    const unsigned* eb = ebuf + (size_t)b * CAP;
    int i = 4 * t;
    for (; i + 3 < cb; i += 1024) {
        uint4 e4 = *(const uint4*)&eb[i];
        atomicAdd(&hc[e4.x >> 17], 1);
        atomicAdd(&hc[e4.y >> 17], 1);
        atomicAdd(&hc[e4.z >> 17], 1);
        atomicAdd(&hc[e4.w >> 17], 1);
    }
    for (; i < cb; ++i) atomicAdd(&hc[eb[i] >> 17], 1);
    __syncthreads();
#pragma unroll
    for (int u = 0; u < 2; ++u) {
        int ii = t + 256 * u;
        sa[ii] = (hc[ii] + 15) & ~15;   // 16-padded count
    }
    __syncthreads();
    // Hillis-Steele inclusive scan over 512 entries (double-buffered)
    int* A = sa;
    int* Bp = sb;
    for (int off = 1; off < 512; off <<= 1) {
#pragma unroll
        for (int u = 0; u < 2; ++u) {
            int ii = t + 256 * u;
            int v = A[ii];
            if (ii >= off) v += A[ii - off];
            Bp[ii] = v;
        }
        __syncthreads();
        int* tmp = A; A = Bp; Bp = tmp;
    }
    // A = inclusive scan of padded counts; Bp = free buffer -> cursors
#pragma unroll
    for (int u = 0; u < 2; ++u) {
        int ii = t + 256 * u;
        int cnt = hc[ii];
        int cp = (cnt + 15) & ~15;
        int excl = A[ii] - cp;
        Bp[ii] = excl;                  // scatter cursor (bucket-local)
        int n = n0 + ii;
        if (n < n_nodes) {
            rowbeg[n] = b * ESCAP + excl;
            degp[n] = cp;
            dinv[n] = rsqrtf((float)cnt + 1.0f);   // true degree + self-loop
        }
    }
    __syncthreads();
    int* es = esrc + (size_t)b * ESCAP;
    i = 4 * t;
    for (; i + 3 < cb; i += 1024) {
        uint4 e4 = *(const uint4*)&eb[i];
#pragma unroll
        for (int u = 0; u < 4; ++u) {
            unsigned e = (&e4.x)[u];
            int r = atomicAdd(&Bp[e >> 17], 1);
            es[r] = (int)(e & 0x1FFFFu);
        }
    }
    for (; i < cb; ++i) {
        unsigned e = eb[i];
        int r = atomicAdd(&Bp[e >> 17], 1);
        es[r] = (int)(e & 0x1FFFFu);
    }
    __syncthreads();
#pragma unroll
    for (int u = 0; u < 2; ++u) {
        int ii = t + 256 * u;
        int end = A[ii];                          // excl + padded count
        for (int p = Bp[ii]; p < end; ++p) es[p] = n_nodes;   // dummy pad
    }
}

// y = fp16((x @ W1) * dinv[n]) via MFMA 16x16x32 f16. Block = 4 waves = 64 rows.
__global__ __launch_bounds__(256, 4) void k_gemm1(
    const float* __restrict__ x, const __half* __restrict__ W1f,
    const float* __restrict__ dinv, __half* __restrict__ y, int n_nodes) {
    __shared__ __half xh[64 * XPAD];
    const int tid = threadIdx.x;
    const int lane = tid & 63;
    const int w = tid >> 6;
    const int row0 = blockIdx.x * 64;

    half8 bf[16];
    const uint4* wf = (const uint4*)W1f;
#pragma unroll
    for (int sc = 0; sc < 16; ++sc) {
        union { uint4 u; half8 h; } tmp;
        tmp.u = wf[sc * 64 + lane];
        bf[sc] = tmp.h;
    }

    for (int i = tid; i < 64 * 32; i += 256) {
        int r = i >> 5, k4 = i & 31;
        int gr = row0 + r;
        if (gr < n_nodes) {
            float4 v = *(const float4*)&x[(size_t)gr * F + 4 * k4];
            __half2 p0 = __floats2half2_rn(v.x, v.y);
            __half2 p1 = __floats2half2_rn(v.z, v.w);
            uint2 pk = make_uint2(*(unsigned*)&p0, *(unsigned*)&p1);
            *(uint2*)&xh[r * XPAD + 4 * k4] = pk;
        }
    }
    __syncthreads();

    const int m16 = lane & 15, quad = lane >> 4;
    floatx4 acc[4];
#pragma unroll
    for (int c = 0; c < 4; ++c) acc[c] = (floatx4){0.f, 0.f, 0.f, 0.f};
#pragma unroll
    for (int s = 0; s < 4; ++s) {
        union { uint4 u; half8 h; } ua;
        ua.u = *(const uint4*)&xh[(16 * w + m16) * XPAD + s * 32 + quad * 8];
#pragma unroll
        for (int c = 0; c < 4; ++c)
            acc[c] = __builtin_amdgcn_mfma_f32_16x16x32_f16(ua.h, bf[s * 4 + c],
                                                            acc[c], 0, 0, 0);
    }
#pragma unroll
    for (int r = 0; r < 4; ++r) {
        int grow = row0 + 16 * w + quad * 4 + r;
        if (grow < n_nodes) {
            float d = dinv[grow];
#pragma unroll
            for (int c = 0; c < 4; ++c)
                y[(size_t)grow * H + c * 16 + m16] = __float2half(acc[c][r] * d);
        }
    }
}

// Fused layer-1 gather + ReLU + W2 projection:
// a[n] = y[n] + sum_k y[esrc[k]]          (fp32, wave-parallel gather)
// h[n] = relu(dinv[n]*a[n] + b1)          (fp32, in-register, all 64 lanes)
// zs[n][j] = fp16(dinv[n] * (h[n] @ W2)[j]), row stride 12 halves, [10..12)=0.
// Wave per node; lane = (group g in [0,4), feature-quad c in [0,16)).
// degp is a multiple of 16 -> branch-free inner loop, 16 edges in flight.
// After the xor-fold every lane holds the full aggregate for its c, so the
// 64x10 dot splits as: group g computes outputs {2g,2g+1}, all groups also
// compute {8,9} (group 0's copy is the one written).
__global__ __launch_bounds__(256) void k_gather1z(
    const uint2* __restrict__ yq, const int* __restrict__ rowbeg,
    const int* __restrict__ degp, const int* __restrict__ esrc,
    const float* __restrict__ dinv, const float* __restrict__ b1,
    const float* __restrict__ W2, unsigned* __restrict__ zs_u, int n_nodes) {
    __shared__ float w2s[H * O];   // 2.56 KB, [k][j] row-major like W2
    for (int i = threadIdx.x; i < H * O; i += 256) w2s[i] = W2[i];
    __syncthreads();
    const int l = threadIdx.x & 63;
    const int g = l >> 4;
    const int c = l & 15;
    const int n = blockIdx.x * 4 + (threadIdx.x >> 6);
    if (n >= n_nodes) return;      // after the only sync: safe
    const int beg = rowbeg[n];
    const int dp = degp[n];
    const int idx = esrc[beg + l];             // coalesced preload (slots >= dp unused)
    float2 aA = make_float2(0.f, 0.f);
    float2 aB = make_float2(0.f, 0.f);
    if (g == 0) {                              // self-loop in group 0 only
        uint2 v = yq[(size_t)n * 16 + c];
        float2 fA = __half22float2(*(const __half2*)&v.x);
        float2 fB = __half22float2(*(const __half2*)&v.y);
        aA.x += fA.x; aA.y += fA.y; aB.x += fB.x; aB.y += fB.y;
    }
    const int dlim = min(dp, 64);
    for (int k = 0; k < dlim; k += 16) {
#pragma unroll
        for (int u = 0; u < 4; ++u) {
            int s = __shfl(idx, k + 4 * u + g, 64);
            uint2 v = yq[(size_t)s * 16 + c];
            float2 fA = __half22float2(*(const __half2*)&v.x);
            float2 fB = __half22float2(*(const __half2*)&v.y);
            aA.x += fA.x; aA.y += fA.y; aB.x += fB.x; aB.y += fB.y;
        }
    }
    for (int kk = 64; kk < dp; kk += 4) {      // rare deg>64 tail (padded, safe)
        int s = esrc[beg + kk + g];
        uint2 v = yq[(size_t)s * 16 + c];
        float2 fA = __half22float2(*(const __half2*)&v.x);
        float2 fB = __half22float2(*(const __half2*)&v.y);
        aA.x += fA.x; aA.y += fA.y; aB.x += fB.x; aB.y += fB.y;
    }
#pragma unroll
    for (int off = 16; off <= 32; off <<= 1) {   // fold 4 edge groups (symmetric:
        aA.x += __shfl_xor(aA.x, off, 64);       // ALL lanes end with the total)
        aA.y += __shfl_xor(aA.y, off, 64);
        aB.x += __shfl_xor(aB.x, off, 64);
        aB.y += __shfl_xor(aB.y, off, 64);
    }
    // h (fp32) in all lanes; lane c holds features 4c..4c+3
    const float4 bb = ((const float4*)b1)[c];
    const float d = dinv[n];
    const float h0 = fmaxf(fmaf(d, aA.x, bb.x), 0.0f);
    const float h1 = fmaxf(fmaf(d, aA.y, bb.y), 0.0f);
    const float h2 = fmaxf(fmaf(d, aB.x, bb.z), 0.0f);
    const float h3 = fmaxf(fmaf(d, aB.y, bb.w), 0.0f);
    // W2 dot: pair qa = {2g, 2g+1}; pair qb = {8, 9} (group 0 writes it)
    const float* wr = &w2s[(4 * c) * O];
    const int ja = 2 * g;
    float sa0 = h0 * wr[0 * O + ja]     + h1 * wr[1 * O + ja]
              + h2 * wr[2 * O + ja]     + h3 * wr[3 * O + ja];
    float sa1 = h0 * wr[0 * O + ja + 1] + h1 * wr[1 * O + ja + 1]
              + h2 * wr[2 * O + ja + 1] + h3 * wr[3 * O + ja + 1];
    float sb0 = h0 * wr[0 * O + 8]      + h1 * wr[1 * O + 8]
              + h2 * wr[2 * O + 8]      + h3 * wr[3 * O + 8];
    float sb1 = h0 * wr[0 * O + 9]      + h1 * wr[1 * O + 9]
              + h2 * wr[2 * O + 9]      + h3 * wr[3 * O + 9];
#pragma unroll
    for (int m = 1; m <= 8; m <<= 1) {           // fold 16 feature-quads
        sa0 += __shfl_xor(sa0, m, 64);
        sa1 += __shfl_xor(sa1, m, 64);
        sb0 += __shfl_xor(sb0, m, 64);
        sb1 += __shfl_xor(sb1, m, 64);
    }
    const size_t rb = (size_t)n * PSU;
    if (c == 0) {                                // lane g*16: outputs {2g,2g+1}
        __half2 pa = __floats2half2_rn(sa0 * d, sa1 * d);
        zs_u[rb + g] = *(const unsigned*)&pa;
    }
    if (l == 1) {                                // outputs {8,9}
        __half2 pb = __floats2half2_rn(sb0 * d, sb1 * d);
        zs_u[rb + 4] = *(const unsigned*)&pb;
    }
    if (l == 2) zs_u[rb + 5] = 0u;               // zero pad uint
}

// out[n][j] = dinv[n] * (zs[n][j] + sum_k zs[esrc[k]][j]) + b2[j]   (fp32 out)
// 8 lanes/node; lanes 5..7 read the zero pad uint -> no inner predicates.
__global__ __launch_bounds__(256) void k_gather2(
    const unsigned* __restrict__ zs_u, const int* __restrict__ rowbeg,
    const int* __restrict__ degp, const int* __restrict__ esrc,
    const float* __restrict__ dinv, const float* __restrict__ b2,
    float* __restrict__ out, int n_nodes) {
    const int l = threadIdx.x & 63;
    const int j = l & 7;
    const int sbase = l & ~7;
    const int jj = (j < 5) ? j : 5;         // pad uint is zero
    const int n = blockIdx.x * 32 + (threadIdx.x >> 3);
    if (n >= n_nodes) return;
    const int beg = rowbeg[n];
    const int dp = degp[n];
    unsigned v0 = zs_u[(size_t)n * PSU + jj];
    float2 acc = __half22float2(*(const __half2*)&v0);
    for (int k0 = 0; k0 < dp; k0 += 8) {
        int idx = esrc[beg + k0 + j];       // unpredicated (dp multiple of 16)
#pragma unroll
        for (int e = 0; e < 8; ++e) {
            int s = __shfl(idx, sbase + e, 64);
            unsigned v = zs_u[(size_t)s * PSU + jj];
            float2 f = __half22float2(*(const __half2*)&v);
            acc.x += f.x;
            acc.y += f.y;
        }
    }
    if (j < 5) {
        float2 bb = ((const float2*)b2)[j];
        float d = dinv[n];
        float2 o = make_float2(fmaf(d, acc.x, bb.x), fmaf(d, acc.y, bb.y));
        *(float2*)&out[(size_t)n * O + 2 * j] = o;
    }
}

static inline size_t align256(size_t v) { return (v + 255) & ~(size_t)255; }

extern "C" void kernel_launch(void* const* d_in, const int* in_sizes, int n_in,
                              void* d_out, int out_size, void* d_ws, size_t ws_size,
                              hipStream_t stream) {
    const float* x  = (const float*)d_in[0];
    const int*   ei = (const int*)d_in[1];
    const float* W1 = (const float*)d_in[2];
    const float* b1 = (const float*)d_in[3];
    const float* W2 = (const float*)d_in[4];
    const float* b2 = (const float*)d_in[5];
    float* out = (float*)d_out;

    const int N = in_sizes[0] / F;   // 100000
    const int E = in_sizes[1] / 2;   // 1600000
    const int* src = ei;
    const int* dst = ei + E;
    const int NBUK = (N + 511) >> 9;            // 196

    // Workspace (bytes): y[(N+1)*H fp16] | scratch-region[N*H fp16] (front
    // aliased by ebuf 9.63MB, consumed by k_bsort; last 16KB = W1f; h no
    // longer materializes) | zs[(N+1)*PSU uints] | dinv[N] | rowbeg[N]
    // | degp[N] | bcntg[256] | esrc[NBUK*ESCAP + 64]
    char* base = (char*)d_ws;
    __half* y = (__half*)base;
    size_t ysz = align256((size_t)(N + 1) * H * 2);
    char* hreg = base + ysz;
    unsigned* ebuf = (unsigned*)hreg;                       // 9.63MB <= 12.78MB
    __half* W1f = (__half*)(hreg + (size_t)N * H * 2 - (size_t)F * H * 2);
    size_t hsz = align256((size_t)N * H * 2);
    char* zreg = hreg + hsz;
    unsigned* zs_u = (unsigned*)zreg;
    size_t zsz = align256((size_t)(N + 1) * PSU * 4);
    float* dinv = (float*)(zreg + zsz);
    int* rowbeg = (int*)(dinv + N);
    int* degp = rowbeg + N;
    int* bcntg = degp + N;
    int* esrc = bcntg + 256;

    const int nb_bin = (E + EPB - 1) / EPB;     // 391

    k_init<<<1 + F * H / 256, 256, 0, stream>>>(bcntg, W1, W1f,
                                                (unsigned*)(y + (size_t)N * H),
                                                zs_u + (size_t)N * PSU);
    k_bin<<<nb_bin, 256, 0, stream>>>(src, dst, bcntg, ebuf, E);
    k_bsort<<<NBUK, 256, 0, stream>>>(ebuf, bcntg, rowbeg, degp, dinv, esrc, N);
    k_gemm1<<<(N + 63) / 64, 256, 0, stream>>>(x, W1f, dinv, y, N);
    k_gather1z<<<(N + 3) / 4, 256, 0, stream>>>((const uint2*)y, rowbeg, degp,
                                                esrc, dinv, b1, W2, zs_u, N);
    k_gather2<<<(N + 31) / 32, 256, 0, stream>>>(zs_u, rowbeg, degp, esrc,
                                                 dinv, b2, out, N);
}

// Round 2
// 189.942 us; speedup vs baseline: 1.1521x; 1.1521x over previous
//
#include <hip/hip_runtime.h>
#include <hip/hip_fp16.h>

// GCN 2-layer forward on gfx950 — CSR-gather with fp16 intermediates (fp32
// accumulation), single-kernel bucketed CSR build with 16-padded edge lists
// (dummy node N has all-zero rows), MFMA layer-1 transform.
// R11: k_gather1z restructured — 8 lanes/node (uint4 row reads, 8 nodes/wave),
// int2 edge-index preload (16 edges/load), W2 transposed in LDS ([10][64],
// 2-way-bank-free float4 reads), per-wave epilogue (was per-node). DS ops/node
// ~54 -> ~9, VMEM instrs halved, bank conflicts (9.6M cyc) eliminated.
// F=128, H=64, O=10. N=100k, E=1.6M.
static constexpr int F = 128;
static constexpr int H = 64;
static constexpr int O = 10;
static constexpr int PSU = 6;          // zs row stride in uints (12 halves, [5]=0 pad)
static constexpr int NBUK_MAX = 256;   // buckets of 512 nodes (dst>>9)
static constexpr int CAP = 12288;      // per-bucket RAW edge capacity (mean 8192, 45σ)
static constexpr int ESCAP = 14336;    // per-bucket PADDED esrc capacity
                                       // (padded mean ~11.7k, σ~180 -> ~14σ headroom)
static constexpr int EPB = 4096;       // edges per block in k_bin
static constexpr int XPAD = 136;       // xh LDS row stride in halves (128 + 8)

typedef _Float16 half8 __attribute__((ext_vector_type(8)));
typedef float floatx4 __attribute__((ext_vector_type(4)));

// block 0: zero bcntg + zero dummy rows (y row N, zs row N);
// blocks 1..32: build W1f = fp16 W1 in MFMA B-fragment order.
__global__ __launch_bounds__(256) void k_init(int* __restrict__ bcntg,
                                              const float* __restrict__ W1,
                                              __half* __restrict__ W1f,
                                              unsigned* __restrict__ yN,
                                              unsigned* __restrict__ zsN) {
    int b = blockIdx.x, t = threadIdx.x;
    if (b == 0) {
        bcntg[t] = 0;
        if (t < 32) yN[t] = 0u;      // y row N: 64 halves
        if (t < PSU) zsN[t] = 0u;    // zs row N
    } else {
        int i = (b - 1) * 256 + t;   // 0..8191
        int j = i & 7, lane = (i >> 3) & 63, sc = i >> 9;
        int s = sc >> 2, c = sc & 3;
        int k = s * 32 + (lane >> 4) * 8 + j;
        int nn = c * 16 + (lane & 15);
        W1f[i] = __float2half(W1[k * H + nn]);
    }
}

// Bin edges by bucket = dst>>9; bucket-contiguous packed 4B entries:
// entry = (dst&511)<<17 | src   (src < 2^17).
__global__ __launch_bounds__(256) void k_bin(const int* __restrict__ src,
                                             const int* __restrict__ dst,
                                             int* __restrict__ bcntg,
                                             unsigned* __restrict__ ebuf, int e_total) {
    __shared__ int hist[NBUK_MAX];
    __shared__ int base[NBUK_MAX];
    __shared__ int loc[NBUK_MAX];
    int t = threadIdx.x;
    hist[t] = 0;
    loc[t] = 0;
    __syncthreads();
    int i0 = blockIdx.x * EPB;
    int i1 = min(i0 + EPB, e_total);
    int i = i0 + 4 * t;
    for (; i + 3 < i1; i += 1024) {
        int4 d4 = *(const int4*)&dst[i];
        atomicAdd(&hist[d4.x >> 9], 1);
        atomicAdd(&hist[d4.y >> 9], 1);
        atomicAdd(&hist[d4.z >> 9], 1);
        atomicAdd(&hist[d4.w >> 9], 1);
    }
    for (; i < i1; ++i) atomicAdd(&hist[dst[i] >> 9], 1);
    __syncthreads();
    if (hist[t] > 0) base[t] = atomicAdd(&bcntg[t], hist[t]);
    __syncthreads();
    i = i0 + 4 * t;
    for (; i + 3 < i1; i += 1024) {
        int4 s4 = *(const int4*)&src[i];
        int4 d4 = *(const int4*)&dst[i];
#pragma unroll
        for (int u = 0; u < 4; ++u) {
            int s = (&s4.x)[u], d = (&d4.x)[u];
            int b = d >> 9;
            int r = base[b] + atomicAdd(&loc[b], 1);
            if (r < CAP)
                ebuf[(size_t)b * CAP + r] = ((unsigned)(d & 511) << 17) | (unsigned)s;
        }
    }
    for (; i < i1; ++i) {
        int s = src[i], d = dst[i];
        int b = d >> 9;
        int r = base[b] + atomicAdd(&loc[b], 1);
        if (r < CAP)
            ebuf[(size_t)b * CAP + r] = ((unsigned)(d & 511) << 17) | (unsigned)s;
    }
}

// One block per bucket: count in-degrees (LDS), LDS-scan 16-padded counts,
// scatter src into bucket-padded esrc (stride ESCAP), pad with dummy node N.
// Emits rowbeg[n] (absolute into esrc), degp[n] (16-padded), dinv[n].
__global__ __launch_bounds__(256) void k_bsort(
    const unsigned* __restrict__ ebuf, const int* __restrict__ bcntg,
    int* __restrict__ rowbeg, int* __restrict__ degp, float* __restrict__ dinv,
    int* __restrict__ esrc, int n_nodes) {
    __shared__ int hc[512];
    __shared__ int sa[512];
    __shared__ int sb[512];
    int t = threadIdx.x, b = blockIdx.x, n0 = b << 9;
    hc[t] = 0;
    hc[t + 256] = 0;
    __syncthreads();
    int cb = min(bcntg[b], CAP);
    const unsigned* eb = ebuf + (size_t)b * CAP;
    int i = 4 * t;
    for (; i + 3 < cb; i += 1024) {
        uint4 e4 = *(const uint4*)&eb[i];
        atomicAdd(&hc[e4.x >> 17], 1);
        atomicAdd(&hc[e4.y >> 17], 1);
        atomicAdd(&hc[e4.z >> 17], 1);
        atomicAdd(&hc[e4.w >> 17], 1);
    }
    for (; i < cb; ++i) atomicAdd(&hc[eb[i] >> 17], 1);
    __syncthreads();
#pragma unroll
    for (int u = 0; u < 2; ++u) {
        int ii = t + 256 * u;
        sa[ii] = (hc[ii] + 15) & ~15;   // 16-padded count
    }
    __syncthreads();
    // Hillis-Steele inclusive scan over 512 entries (double-buffered)
    int* A = sa;
    int* Bp = sb;
    for (int off = 1; off < 512; off <<= 1) {
#pragma unroll
        for (int u = 0; u < 2; ++u) {
            int ii = t + 256 * u;
            int v = A[ii];
            if (ii >= off) v += A[ii - off];
            Bp[ii] = v;
        }
        __syncthreads();
        int* tmp = A; A = Bp; Bp = tmp;
    }
    // A = inclusive scan of padded counts; Bp = free buffer -> cursors
#pragma unroll
    for (int u = 0; u < 2; ++u) {
        int ii = t + 256 * u;
        int cnt = hc[ii];
        int cp = (cnt + 15) & ~15;
        int excl = A[ii] - cp;
        Bp[ii] = excl;                  // scatter cursor (bucket-local)
        int n = n0 + ii;
        if (n < n_nodes) {
            rowbeg[n] = b * ESCAP + excl;
            degp[n] = cp;
            dinv[n] = rsqrtf((float)cnt + 1.0f);   // true degree + self-loop
        }
    }
    __syncthreads();
    int* es = esrc + (size_t)b * ESCAP;
    i = 4 * t;
    for (; i + 3 < cb; i += 1024) {
        uint4 e4 = *(const uint4*)&eb[i];
#pragma unroll
        for (int u = 0; u < 4; ++u) {
            unsigned e = (&e4.x)[u];
            int r = atomicAdd(&Bp[e >> 17], 1);
            es[r] = (int)(e & 0x1FFFFu);
        }
    }
    for (; i < cb; ++i) {
        unsigned e = eb[i];
        int r = atomicAdd(&Bp[e >> 17], 1);
        es[r] = (int)(e & 0x1FFFFu);
    }
    __syncthreads();
#pragma unroll
    for (int u = 0; u < 2; ++u) {
        int ii = t + 256 * u;
        int end = A[ii];                          // excl + padded count
        for (int p = Bp[ii]; p < end; ++p) es[p] = n_nodes;   // dummy pad
    }
}

// y = fp16((x @ W1) * dinv[n]) via MFMA 16x16x32 f16. Block = 4 waves = 64 rows.
__global__ __launch_bounds__(256, 4) void k_gemm1(
    const float* __restrict__ x, const __half* __restrict__ W1f,
    const float* __restrict__ dinv, __half* __restrict__ y, int n_nodes) {
    __shared__ __half xh[64 * XPAD];
    const int tid = threadIdx.x;
    const int lane = tid & 63;
    const int w = tid >> 6;
    const int row0 = blockIdx.x * 64;

    half8 bf[16];
    const uint4* wf = (const uint4*)W1f;
#pragma unroll
    for (int sc = 0; sc < 16; ++sc) {
        union { uint4 u; half8 h; } tmp;
        tmp.u = wf[sc * 64 + lane];
        bf[sc] = tmp.h;
    }

    for (int i = tid; i < 64 * 32; i += 256) {
        int r = i >> 5, k4 = i & 31;
        int gr = row0 + r;
        if (gr < n_nodes) {
            float4 v = *(const float4*)&x[(size_t)gr * F + 4 * k4];
            __half2 p0 = __floats2half2_rn(v.x, v.y);
            __half2 p1 = __floats2half2_rn(v.z, v.w);
            uint2 pk = make_uint2(*(unsigned*)&p0, *(unsigned*)&p1);
            *(uint2*)&xh[r * XPAD + 4 * k4] = pk;
        }
    }
    __syncthreads();

    const int m16 = lane & 15, quad = lane >> 4;
    floatx4 acc[4];
#pragma unroll
    for (int c = 0; c < 4; ++c) acc[c] = (floatx4){0.f, 0.f, 0.f, 0.f};
#pragma unroll
    for (int s = 0; s < 4; ++s) {
        union { uint4 u; half8 h; } ua;
        ua.u = *(const uint4*)&xh[(16 * w + m16) * XPAD + s * 32 + quad * 8];
#pragma unroll
        for (int c = 0; c < 4; ++c)
            acc[c] = __builtin_amdgcn_mfma_f32_16x16x32_f16(ua.h, bf[s * 4 + c],
                                                            acc[c], 0, 0, 0);
    }
#pragma unroll
    for (int r = 0; r < 4; ++r) {
        int grow = row0 + 16 * w + quad * 4 + r;
        if (grow < n_nodes) {
            float d = dinv[grow];
#pragma unroll
            for (int c = 0; c < 4; ++c)
                y[(size_t)grow * H + c * 16 + m16] = __float2half(acc[c][r] * d);
        }
    }
}

// Fused layer-1 gather + ReLU + W2 projection (R11 structure):
// 8 lanes/node (lane octet c in [0,8) owns features 8c..8c+7), 8 nodes/wave,
// 32 nodes/block. Row reads are uint4 (16B x 8 lanes = full 128B y row).
// Edge indices preloaded as int2 (16 edges per load; degp is a multiple of 16).
// Epilogue: h = relu(dinv*agg + b1) in regs; per-lane partials for ALL 10
// outputs vs W2 staged transposed in LDS [10][64] (float4 reads, lane stride
// 32B -> 2-way bank aliasing = free, cross-group broadcast); 3-step xor fold
// within the 8-lane group; lane c==0 stores the packed 24B zs row.
__global__ __launch_bounds__(256) void k_gather1z(
    const uint4* __restrict__ yq4, const int* __restrict__ rowbeg,
    const int* __restrict__ degp, const int* __restrict__ esrc,
    const float* __restrict__ dinv, const float* __restrict__ b1,
    const float* __restrict__ W2, unsigned* __restrict__ zs_u, int n_nodes) {
    __shared__ float w2t[O * H];   // 2.56 KB, transposed: w2t[j*64+k] = W2[k*10+j]
    for (int i = threadIdx.x; i < O * H; i += 256)
        w2t[i] = W2[(i & 63) * O + (i >> 6)];
    __syncthreads();
    const int l = threadIdx.x & 63;
    const int c = l & 7;            // feature octet
    const int gbase = l & ~7;       // first lane of this node's group
    const int n = blockIdx.x * 32 + (threadIdx.x >> 3);
    if (n >= n_nodes) return;       // after the only sync: safe
    const int beg = rowbeg[n];
    const int dp = degp[n];
    const float d = dinv[n];

    float acc[8];
    {   // self-loop: whole group adds its own node's row
        uint4 v = yq4[(size_t)n * 8 + c];
        float2 f0 = __half22float2(*(const __half2*)&v.x);
        float2 f1 = __half22float2(*(const __half2*)&v.y);
        float2 f2 = __half22float2(*(const __half2*)&v.z);
        float2 f3 = __half22float2(*(const __half2*)&v.w);
        acc[0] = f0.x; acc[1] = f0.y; acc[2] = f1.x; acc[3] = f1.y;
        acc[4] = f2.x; acc[5] = f2.y; acc[6] = f3.x; acc[7] = f3.y;
    }
    for (int k0 = 0; k0 < dp; k0 += 16) {
        int2 idx = *(const int2*)&esrc[beg + k0 + 2 * c];   // 16 edges (aligned:
#pragma unroll                                              //  beg,dp mult of 16)
        for (int e = 0; e < 16; ++e) {
            int s = __shfl((e & 1) ? idx.y : idx.x, gbase + (e >> 1), 64);
            uint4 v = yq4[(size_t)s * 8 + c];
            float2 f0 = __half22float2(*(const __half2*)&v.x);
            float2 f1 = __half22float2(*(const __half2*)&v.y);
            float2 f2 = __half22float2(*(const __half2*)&v.z);
            float2 f3 = __half22float2(*(const __half2*)&v.w);
            acc[0] += f0.x; acc[1] += f0.y; acc[2] += f1.x; acc[3] += f1.y;
            acc[4] += f2.x; acc[5] += f2.y; acc[6] += f3.x; acc[7] += f3.y;
        }
    }
    // h (fp32) for this lane's feature octet
    const float4 ba = ((const float4*)b1)[2 * c];
    const float4 bbv = ((const float4*)b1)[2 * c + 1];
    float h[8];
    h[0] = fmaxf(fmaf(d, acc[0], ba.x), 0.0f);
    h[1] = fmaxf(fmaf(d, acc[1], ba.y), 0.0f);
    h[2] = fmaxf(fmaf(d, acc[2], ba.z), 0.0f);
    h[3] = fmaxf(fmaf(d, acc[3], ba.w), 0.0f);
    h[4] = fmaxf(fmaf(d, acc[4], bbv.x), 0.0f);
    h[5] = fmaxf(fmaf(d, acc[5], bbv.y), 0.0f);
    h[6] = fmaxf(fmaf(d, acc[6], bbv.z), 0.0f);
    h[7] = fmaxf(fmaf(d, acc[7], bbv.w), 0.0f);
    // per-lane partials for all 10 outputs (indices compile-time after unroll)
    float p[O];
#pragma unroll
    for (int j = 0; j < O; ++j) {
        float4 wa = *(const float4*)&w2t[j * 64 + 8 * c];
        float4 wb = *(const float4*)&w2t[j * 64 + 8 * c + 4];
        p[j] = h[0] * wa.x + h[1] * wa.y + h[2] * wa.z + h[3] * wa.w
             + h[4] * wb.x + h[5] * wb.y + h[6] * wb.z + h[7] * wb.w;
    }
#pragma unroll
    for (int m = 1; m <= 4; m <<= 1) {      // fold the 8-lane group
#pragma unroll
        for (int j = 0; j < O; ++j) p[j] += __shfl_xor(p[j], m, 64);
    }
    if (c == 0) {
        __half2 q0 = __floats2half2_rn(p[0] * d, p[1] * d);
        __half2 q1 = __floats2half2_rn(p[2] * d, p[3] * d);
        __half2 q2 = __floats2half2_rn(p[4] * d, p[5] * d);
        __half2 q3 = __floats2half2_rn(p[6] * d, p[7] * d);
        __half2 q4 = __floats2half2_rn(p[8] * d, p[9] * d);
        uint2* zp = (uint2*)&zs_u[(size_t)n * PSU];   // n*24B, 8B-aligned
        zp[0] = make_uint2(*(const unsigned*)&q0, *(const unsigned*)&q1);
        zp[1] = make_uint2(*(const unsigned*)&q2, *(const unsigned*)&q3);
        zp[2] = make_uint2(*(const unsigned*)&q4, 0u);   // zero pad uint
    }
}

// out[n][j] = dinv[n] * (zs[n][j] + sum_k zs[esrc[k]][j]) + b2[j]   (fp32 out)
// 8 lanes/node; lanes 5..7 read the zero pad uint -> no inner predicates.
__global__ __launch_bounds__(256) void k_gather2(
    const unsigned* __restrict__ zs_u, const int* __restrict__ rowbeg,
    const int* __restrict__ degp, const int* __restrict__ esrc,
    const float* __restrict__ dinv, const float* __restrict__ b2,
    float* __restrict__ out, int n_nodes) {
    const int l = threadIdx.x & 63;
    const int j = l & 7;
    const int sbase = l & ~7;
    const int jj = (j < 5) ? j : 5;         // pad uint is zero
    const int n = blockIdx.x * 32 + (threadIdx.x >> 3);
    if (n >= n_nodes) return;
    const int beg = rowbeg[n];
    const int dp = degp[n];
    unsigned v0 = zs_u[(size_t)n * PSU + jj];
    float2 acc = __half22float2(*(const __half2*)&v0);
    for (int k0 = 0; k0 < dp; k0 += 8) {
        int idx = esrc[beg + k0 + j];       // unpredicated (dp multiple of 16)
#pragma unroll
        for (int e = 0; e < 8; ++e) {
            int s = __shfl(idx, sbase + e, 64);
            unsigned v = zs_u[(size_t)s * PSU + jj];
            float2 f = __half22float2(*(const __half2*)&v);
            acc.x += f.x;
            acc.y += f.y;
        }
    }
    if (j < 5) {
        float2 bb = ((const float2*)b2)[j];
        float d = dinv[n];
        float2 o = make_float2(fmaf(d, acc.x, bb.x), fmaf(d, acc.y, bb.y));
        *(float2*)&out[(size_t)n * O + 2 * j] = o;
    }
}

static inline size_t align256(size_t v) { return (v + 255) & ~(size_t)255; }

extern "C" void kernel_launch(void* const* d_in, const int* in_sizes, int n_in,
                              void* d_out, int out_size, void* d_ws, size_t ws_size,
                              hipStream_t stream) {
    const float* x  = (const float*)d_in[0];
    const int*   ei = (const int*)d_in[1];
    const float* W1 = (const float*)d_in[2];
    const float* b1 = (const float*)d_in[3];
    const float* W2 = (const float*)d_in[4];
    const float* b2 = (const float*)d_in[5];
    float* out = (float*)d_out;

    const int N = in_sizes[0] / F;   // 100000
    const int E = in_sizes[1] / 2;   // 1600000
    const int* src = ei;
    const int* dst = ei + E;
    const int NBUK = (N + 511) >> 9;            // 196

    // Workspace (bytes): y[(N+1)*H fp16] | scratch-region[N*H fp16] (front
    // aliased by ebuf 9.63MB, consumed by k_bsort; last 16KB = W1f; h no
    // longer materializes) | zs[(N+1)*PSU uints] | dinv[N] | rowbeg[N]
    // | degp[N] | bcntg[256] | esrc[NBUK*ESCAP + 64]
    char* base = (char*)d_ws;
    __half* y = (__half*)base;
    size_t ysz = align256((size_t)(N + 1) * H * 2);
    char* hreg = base + ysz;
    unsigned* ebuf = (unsigned*)hreg;                       // 9.63MB <= 12.78MB
    __half* W1f = (__half*)(hreg + (size_t)N * H * 2 - (size_t)F * H * 2);
    size_t hsz = align256((size_t)N * H * 2);
    char* zreg = hreg + hsz;
    unsigned* zs_u = (unsigned*)zreg;
    size_t zsz = align256((size_t)(N + 1) * PSU * 4);
    float* dinv = (float*)(zreg + zsz);
    int* rowbeg = (int*)(dinv + N);
    int* degp = rowbeg + N;
    int* bcntg = degp + N;
    int* esrc = bcntg + 256;

    const int nb_bin = (E + EPB - 1) / EPB;     // 391

    k_init<<<1 + F * H / 256, 256, 0, stream>>>(bcntg, W1, W1f,
                                                (unsigned*)(y + (size_t)N * H),
                                                zs_u + (size_t)N * PSU);
    k_bin<<<nb_bin, 256, 0, stream>>>(src, dst, bcntg, ebuf, E);
    k_bsort<<<NBUK, 256, 0, stream>>>(ebuf, bcntg, rowbeg, degp, dinv, esrc, N);
    k_gemm1<<<(N + 63) / 64, 256, 0, stream>>>(x, W1f, dinv, y, N);
    k_gather1z<<<(N + 31) / 32, 256, 0, stream>>>((const uint4*)y, rowbeg, degp,
                                                  esrc, dinv, b1, W2, zs_u, N);
    k_gather2<<<(N + 31) / 32, 256, 0, stream>>>(zs_u, rowbeg, degp, esrc,
                                                 dinv, b2, out, N);
}

// Round 3
// 188.888 us; speedup vs baseline: 1.1585x; 1.0056x over previous
//
#include <hip/hip_runtime.h>
#include <hip/hip_fp16.h>

// GCN 2-layer forward on gfx950 — CSR-gather with fp16 intermediates (fp32
// accumulation), single-kernel bucketed CSR build with 8-padded edge lists
// (dummy node N has all-zero rows), MFMA layer-1 transform, W2 projection
// fused into the layer-1 gather epilogue (h never materializes).
// R12: pad granularity 16 -> 8 (mean padded deg 23.5 -> 20.4, −13% gather
// iterations); k_gather2 4 lanes/node via uint2 zs reads (16 nodes/wave,
// ~40% fewer issue slots/edge; lane 3 is a spectator — no fold exists, so
// its accumulator is discarded, no masking needed).
// F=128, H=64, O=10. N=100k, E=1.6M.
static constexpr int F = 128;
static constexpr int H = 64;
static constexpr int O = 10;
static constexpr int PSU = 6;          // zs row stride in uints (12 halves, [5]=0 pad)
static constexpr int NBUK_MAX = 256;   // buckets of 512 nodes (dst>>9)
static constexpr int CAP = 12288;      // per-bucket RAW edge capacity (mean 8192, 45σ)
static constexpr int ESCAP = 14336;    // per-bucket PADDED esrc capacity
                                       // (pad-8 mean ~10.45k, huge headroom)
static constexpr int EPB = 4096;       // edges per block in k_bin
static constexpr int XPAD = 136;       // xh LDS row stride in halves (128 + 8)

typedef _Float16 half8 __attribute__((ext_vector_type(8)));
typedef float floatx4 __attribute__((ext_vector_type(4)));

// block 0: zero bcntg + zero dummy rows (y row N, zs row N);
// blocks 1..32: build W1f = fp16 W1 in MFMA B-fragment order.
__global__ __launch_bounds__(256) void k_init(int* __restrict__ bcntg,
                                              const float* __restrict__ W1,
                                              __half* __restrict__ W1f,
                                              unsigned* __restrict__ yN,
                                              unsigned* __restrict__ zsN) {
    int b = blockIdx.x, t = threadIdx.x;
    if (b == 0) {
        bcntg[t] = 0;
        if (t < 32) yN[t] = 0u;      // y row N: 64 halves
        if (t < PSU) zsN[t] = 0u;    // zs row N
    } else {
        int i = (b - 1) * 256 + t;   // 0..8191
        int j = i & 7, lane = (i >> 3) & 63, sc = i >> 9;
        int s = sc >> 2, c = sc & 3;
        int k = s * 32 + (lane >> 4) * 8 + j;
        int nn = c * 16 + (lane & 15);
        W1f[i] = __float2half(W1[k * H + nn]);
    }
}

// Bin edges by bucket = dst>>9; bucket-contiguous packed 4B entries:
// entry = (dst&511)<<17 | src   (src < 2^17).
__global__ __launch_bounds__(256) void k_bin(const int* __restrict__ src,
                                             const int* __restrict__ dst,
                                             int* __restrict__ bcntg,
                                             unsigned* __restrict__ ebuf, int e_total) {
    __shared__ int hist[NBUK_MAX];
    __shared__ int base[NBUK_MAX];
    __shared__ int loc[NBUK_MAX];
    int t = threadIdx.x;
    hist[t] = 0;
    loc[t] = 0;
    __syncthreads();
    int i0 = blockIdx.x * EPB;
    int i1 = min(i0 + EPB, e_total);
    int i = i0 + 4 * t;
    for (; i + 3 < i1; i += 1024) {
        int4 d4 = *(const int4*)&dst[i];
        atomicAdd(&hist[d4.x >> 9], 1);
        atomicAdd(&hist[d4.y >> 9], 1);
        atomicAdd(&hist[d4.z >> 9], 1);
        atomicAdd(&hist[d4.w >> 9], 1);
    }
    for (; i < i1; ++i) atomicAdd(&hist[dst[i] >> 9], 1);
    __syncthreads();
    if (hist[t] > 0) base[t] = atomicAdd(&bcntg[t], hist[t]);
    __syncthreads();
    i = i0 + 4 * t;
    for (; i + 3 < i1; i += 1024) {
        int4 s4 = *(const int4*)&src[i];
        int4 d4 = *(const int4*)&dst[i];
#pragma unroll
        for (int u = 0; u < 4; ++u) {
            int s = (&s4.x)[u], d = (&d4.x)[u];
            int b = d >> 9;
            int r = base[b] + atomicAdd(&loc[b], 1);
            if (r < CAP)
                ebuf[(size_t)b * CAP + r] = ((unsigned)(d & 511) << 17) | (unsigned)s;
        }
    }
    for (; i < i1; ++i) {
        int s = src[i], d = dst[i];
        int b = d >> 9;
        int r = base[b] + atomicAdd(&loc[b], 1);
        if (r < CAP)
            ebuf[(size_t)b * CAP + r] = ((unsigned)(d & 511) << 17) | (unsigned)s;
    }
}

// One block per bucket: count in-degrees (LDS), LDS-scan 8-padded counts,
// scatter src into bucket-padded esrc (stride ESCAP), pad with dummy node N.
// Emits rowbeg[n] (absolute into esrc), degp[n] (8-padded), dinv[n].
__global__ __launch_bounds__(256) void k_bsort(
    const unsigned* __restrict__ ebuf, const int* __restrict__ bcntg,
    int* __restrict__ rowbeg, int* __restrict__ degp, float* __restrict__ dinv,
    int* __restrict__ esrc, int n_nodes) {
    __shared__ int hc[512];
    __shared__ int sa[512];
    __shared__ int sb[512];
    int t = threadIdx.x, b = blockIdx.x, n0 = b << 9;
    hc[t] = 0;
    hc[t + 256] = 0;
    __syncthreads();
    int cb = min(bcntg[b], CAP);
    const unsigned* eb = ebuf + (size_t)b * CAP;
    int i = 4 * t;
    for (; i + 3 < cb; i += 1024) {
        uint4 e4 = *(const uint4*)&eb[i];
        atomicAdd(&hc[e4.x >> 17], 1);
        atomicAdd(&hc[e4.y >> 17], 1);
        atomicAdd(&hc[e4.z >> 17], 1);
        atomicAdd(&hc[e4.w >> 17], 1);
    }
    for (; i < cb; ++i) atomicAdd(&hc[eb[i] >> 17], 1);
    __syncthreads();
#pragma unroll
    for (int u = 0; u < 2; ++u) {
        int ii = t + 256 * u;
        sa[ii] = (hc[ii] + 7) & ~7;     // 8-padded count
    }
    __syncthreads();
    // Hillis-Steele inclusive scan over 512 entries (double-buffered)
    int* A = sa;
    int* Bp = sb;
    for (int off = 1; off < 512; off <<= 1) {
#pragma unroll
        for (int u = 0; u < 2; ++u) {
            int ii = t + 256 * u;
            int v = A[ii];
            if (ii >= off) v += A[ii - off];
            Bp[ii] = v;
        }
        __syncthreads();
        int* tmp = A; A = Bp; Bp = tmp;
    }
    // A = inclusive scan of padded counts; Bp = free buffer -> cursors
#pragma unroll
    for (int u = 0; u < 2; ++u) {
        int ii = t + 256 * u;
        int cnt = hc[ii];
        int cp = (cnt + 7) & ~7;
        int excl = A[ii] - cp;
        Bp[ii] = excl;                  // scatter cursor (bucket-local)
        int n = n0 + ii;
        if (n < n_nodes) {
            rowbeg[n] = b * ESCAP + excl;
            degp[n] = cp;
            dinv[n] = rsqrtf((float)cnt + 1.0f);   // true degree + self-loop
        }
    }
    __syncthreads();
    int* es = esrc + (size_t)b * ESCAP;
    i = 4 * t;
    for (; i + 3 < cb; i += 1024) {
        uint4 e4 = *(const uint4*)&eb[i];
#pragma unroll
        for (int u = 0; u < 4; ++u) {
            unsigned e = (&e4.x)[u];
            int r = atomicAdd(&Bp[e >> 17], 1);
            es[r] = (int)(e & 0x1FFFFu);
        }
    }
    for (; i < cb; ++i) {
        unsigned e = eb[i];
        int r = atomicAdd(&Bp[e >> 17], 1);
        es[r] = (int)(e & 0x1FFFFu);
    }
    __syncthreads();
#pragma unroll
    for (int u = 0; u < 2; ++u) {
        int ii = t + 256 * u;
        int end = A[ii];                          // excl + padded count
        for (int p = Bp[ii]; p < end; ++p) es[p] = n_nodes;   // dummy pad
    }
}

// y = fp16((x @ W1) * dinv[n]) via MFMA 16x16x32 f16. Block = 4 waves = 64 rows.
__global__ __launch_bounds__(256, 4) void k_gemm1(
    const float* __restrict__ x, const __half* __restrict__ W1f,
    const float* __restrict__ dinv, __half* __restrict__ y, int n_nodes) {
    __shared__ __half xh[64 * XPAD];
    const int tid = threadIdx.x;
    const int lane = tid & 63;
    const int w = tid >> 6;
    const int row0 = blockIdx.x * 64;

    half8 bf[16];
    const uint4* wf = (const uint4*)W1f;
#pragma unroll
    for (int sc = 0; sc < 16; ++sc) {
        union { uint4 u; half8 h; } tmp;
        tmp.u = wf[sc * 64 + lane];
        bf[sc] = tmp.h;
    }

    for (int i = tid; i < 64 * 32; i += 256) {
        int r = i >> 5, k4 = i & 31;
        int gr = row0 + r;
        if (gr < n_nodes) {
            float4 v = *(const float4*)&x[(size_t)gr * F + 4 * k4];
            __half2 p0 = __floats2half2_rn(v.x, v.y);
            __half2 p1 = __floats2half2_rn(v.z, v.w);
            uint2 pk = make_uint2(*(unsigned*)&p0, *(unsigned*)&p1);
            *(uint2*)&xh[r * XPAD + 4 * k4] = pk;
        }
    }
    __syncthreads();

    const int m16 = lane & 15, quad = lane >> 4;
    floatx4 acc[4];
#pragma unroll
    for (int c = 0; c < 4; ++c) acc[c] = (floatx4){0.f, 0.f, 0.f, 0.f};
#pragma unroll
    for (int s = 0; s < 4; ++s) {
        union { uint4 u; half8 h; } ua;
        ua.u = *(const uint4*)&xh[(16 * w + m16) * XPAD + s * 32 + quad * 8];
#pragma unroll
        for (int c = 0; c < 4; ++c)
            acc[c] = __builtin_amdgcn_mfma_f32_16x16x32_f16(ua.h, bf[s * 4 + c],
                                                            acc[c], 0, 0, 0);
    }
#pragma unroll
    for (int r = 0; r < 4; ++r) {
        int grow = row0 + 16 * w + quad * 4 + r;
        if (grow < n_nodes) {
            float d = dinv[grow];
#pragma unroll
            for (int c = 0; c < 4; ++c)
                y[(size_t)grow * H + c * 16 + m16] = __float2half(acc[c][r] * d);
        }
    }
}

// Fused layer-1 gather + ReLU + W2 projection:
// 8 lanes/node (lane octet c in [0,8) owns features 8c..8c+7), 8 nodes/wave,
// 32 nodes/block. Row reads are uint4 (16B x 8 lanes = full 128B y row).
// 8 edge indices per batch (one scalar esrc load per lane; degp mult of 8).
// Epilogue: h = relu(dinv*agg + b1) in regs; per-lane partials for ALL 10
// outputs vs W2 staged transposed in LDS [10][64] (float4 reads, lane stride
// 32B -> 2-way bank aliasing = free, cross-group broadcast); 3-step xor fold
// within the 8-lane group; lane c==0 stores the packed 24B zs row.
__global__ __launch_bounds__(256) void k_gather1z(
    const uint4* __restrict__ yq4, const int* __restrict__ rowbeg,
    const int* __restrict__ degp, const int* __restrict__ esrc,
    const float* __restrict__ dinv, const float* __restrict__ b1,
    const float* __restrict__ W2, unsigned* __restrict__ zs_u, int n_nodes) {
    __shared__ float w2t[O * H];   // 2.56 KB, transposed: w2t[j*64+k] = W2[k*10+j]
    for (int i = threadIdx.x; i < O * H; i += 256)
        w2t[i] = W2[(i & 63) * O + (i >> 6)];
    __syncthreads();
    const int l = threadIdx.x & 63;
    const int c = l & 7;            // feature octet
    const int gbase = l & ~7;       // first lane of this node's group
    const int n = blockIdx.x * 32 + (threadIdx.x >> 3);
    if (n >= n_nodes) return;       // after the only sync: safe
    const int beg = rowbeg[n];
    const int dp = degp[n];
    const float d = dinv[n];

    float acc[8];
    {   // self-loop: whole group adds its own node's row
        uint4 v = yq4[(size_t)n * 8 + c];
        float2 f0 = __half22float2(*(const __half2*)&v.x);
        float2 f1 = __half22float2(*(const __half2*)&v.y);
        float2 f2 = __half22float2(*(const __half2*)&v.z);
        float2 f3 = __half22float2(*(const __half2*)&v.w);
        acc[0] = f0.x; acc[1] = f0.y; acc[2] = f1.x; acc[3] = f1.y;
        acc[4] = f2.x; acc[5] = f2.y; acc[6] = f3.x; acc[7] = f3.y;
    }
    for (int k0 = 0; k0 < dp; k0 += 8) {
        int idx = esrc[beg + k0 + c];    // 8 edges (beg,dp multiples of 8)
#pragma unroll
        for (int e = 0; e < 8; ++e) {
            int s = __shfl(idx, gbase + e, 64);
            uint4 v = yq4[(size_t)s * 8 + c];
            float2 f0 = __half22float2(*(const __half2*)&v.x);
            float2 f1 = __half22float2(*(const __half2*)&v.y);
            float2 f2 = __half22float2(*(const __half2*)&v.z);
            float2 f3 = __half22float2(*(const __half2*)&v.w);
            acc[0] += f0.x; acc[1] += f0.y; acc[2] += f1.x; acc[3] += f1.y;
            acc[4] += f2.x; acc[5] += f2.y; acc[6] += f3.x; acc[7] += f3.y;
        }
    }
    // h (fp32) for this lane's feature octet
    const float4 ba = ((const float4*)b1)[2 * c];
    const float4 bbv = ((const float4*)b1)[2 * c + 1];
    float h[8];
    h[0] = fmaxf(fmaf(d, acc[0], ba.x), 0.0f);
    h[1] = fmaxf(fmaf(d, acc[1], ba.y), 0.0f);
    h[2] = fmaxf(fmaf(d, acc[2], ba.z), 0.0f);
    h[3] = fmaxf(fmaf(d, acc[3], ba.w), 0.0f);
    h[4] = fmaxf(fmaf(d, acc[4], bbv.x), 0.0f);
    h[5] = fmaxf(fmaf(d, acc[5], bbv.y), 0.0f);
    h[6] = fmaxf(fmaf(d, acc[6], bbv.z), 0.0f);
    h[7] = fmaxf(fmaf(d, acc[7], bbv.w), 0.0f);
    // per-lane partials for all 10 outputs (indices compile-time after unroll)
    float p[O];
#pragma unroll
    for (int j = 0; j < O; ++j) {
        float4 wa = *(const float4*)&w2t[j * 64 + 8 * c];
        float4 wb = *(const float4*)&w2t[j * 64 + 8 * c + 4];
        p[j] = h[0] * wa.x + h[1] * wa.y + h[2] * wa.z + h[3] * wa.w
             + h[4] * wb.x + h[5] * wb.y + h[6] * wb.z + h[7] * wb.w;
    }
#pragma unroll
    for (int m = 1; m <= 4; m <<= 1) {      // fold the 8-lane group
#pragma unroll
        for (int j = 0; j < O; ++j) p[j] += __shfl_xor(p[j], m, 64);
    }
    if (c == 0) {
        __half2 q0 = __floats2half2_rn(p[0] * d, p[1] * d);
        __half2 q1 = __floats2half2_rn(p[2] * d, p[3] * d);
        __half2 q2 = __floats2half2_rn(p[4] * d, p[5] * d);
        __half2 q3 = __floats2half2_rn(p[6] * d, p[7] * d);
        __half2 q4 = __floats2half2_rn(p[8] * d, p[9] * d);
        uint2* zp = (uint2*)&zs_u[(size_t)n * PSU];   // n*24B, 8B-aligned
        zp[0] = make_uint2(*(const unsigned*)&q0, *(const unsigned*)&q1);
        zp[1] = make_uint2(*(const unsigned*)&q2, *(const unsigned*)&q3);
        zp[2] = make_uint2(*(const unsigned*)&q4, 0u);   // zero pad uint
    }
}

// out[n][j] = dinv[n] * (zs[n][j] + sum_k zs[esrc[k]][j]) + b2[j]   (fp32 out)
// 4 lanes/node, uint2 zs reads (lane j owns output pairs {2j,2j+1}); 16
// nodes/wave, 64 nodes/block. Lane 3 re-reads slot 2 — there is NO cross-lane
// fold, its accumulator is never written, so no masking/redirect is needed.
__global__ __launch_bounds__(256) void k_gather2(
    const unsigned* __restrict__ zs_u, const int* __restrict__ rowbeg,
    const int* __restrict__ degp, const int* __restrict__ esrc,
    const float* __restrict__ dinv, const float* __restrict__ b2,
    float* __restrict__ out, int n_nodes) {
    const int l = threadIdx.x & 63;
    const int j = l & 3;
    const int gb = l & ~3;
    const int jj = (j < 3) ? j : 2;         // lane 3: spectator (dup of slot 2)
    const int n = blockIdx.x * 64 + (threadIdx.x >> 2);
    if (n >= n_nodes) return;
    const int beg = rowbeg[n];
    const int dp = degp[n];
    uint2 v0 = *(const uint2*)&zs_u[(size_t)n * PSU + 2 * jj];
    float2 accA = __half22float2(*(const __half2*)&v0.x);
    float2 accB = __half22float2(*(const __half2*)&v0.y);
    for (int k0 = 0; k0 < dp; k0 += 8) {
        int2 idx = *(const int2*)&esrc[beg + k0 + 2 * j];   // 8 edges (8B-aligned)
#pragma unroll
        for (int e = 0; e < 8; ++e) {
            int s = __shfl((e & 1) ? idx.y : idx.x, gb + (e >> 1), 64);
            uint2 v = *(const uint2*)&zs_u[(size_t)s * PSU + 2 * jj];
            float2 fA = __half22float2(*(const __half2*)&v.x);
            float2 fB = __half22float2(*(const __half2*)&v.y);
            accA.x += fA.x; accA.y += fA.y;
            accB.x += fB.x; accB.y += fB.y;
        }
    }
    if (j < 3) {
        const float d = dinv[n];
        float2 bbA = ((const float2*)b2)[2 * j];
        float2 oA = make_float2(fmaf(d, accA.x, bbA.x), fmaf(d, accA.y, bbA.y));
        *(float2*)&out[(size_t)n * O + 4 * j] = oA;       // outputs 4j,4j+1
        if (j < 2) {
            float2 bbB = ((const float2*)b2)[2 * j + 1];
            float2 oB = make_float2(fmaf(d, accB.x, bbB.x), fmaf(d, accB.y, bbB.y));
            *(float2*)&out[(size_t)n * O + 4 * j + 2] = oB;   // outputs 4j+2,4j+3
        }
    }
}

static inline size_t align256(size_t v) { return (v + 255) & ~(size_t)255; }

extern "C" void kernel_launch(void* const* d_in, const int* in_sizes, int n_in,
                              void* d_out, int out_size, void* d_ws, size_t ws_size,
                              hipStream_t stream) {
    const float* x  = (const float*)d_in[0];
    const int*   ei = (const int*)d_in[1];
    const float* W1 = (const float*)d_in[2];
    const float* b1 = (const float*)d_in[3];
    const float* W2 = (const float*)d_in[4];
    const float* b2 = (const float*)d_in[5];
    float* out = (float*)d_out;

    const int N = in_sizes[0] / F;   // 100000
    const int E = in_sizes[1] / 2;   // 1600000
    const int* src = ei;
    const int* dst = ei + E;
    const int NBUK = (N + 511) >> 9;            // 196

    // Workspace (bytes): y[(N+1)*H fp16] | scratch-region[N*H fp16] (front
    // aliased by ebuf 9.63MB, consumed by k_bsort; last 16KB = W1f) | zs[(N+1)
    // *PSU uints] | dinv[N] | rowbeg[N] | degp[N] | bcntg[256]
    // | esrc[NBUK*ESCAP + 64]
    char* base = (char*)d_ws;
    __half* y = (__half*)base;
    size_t ysz = align256((size_t)(N + 1) * H * 2);
    char* hreg = base + ysz;
    unsigned* ebuf = (unsigned*)hreg;                       // 9.63MB <= 12.78MB
    __half* W1f = (__half*)(hreg + (size_t)N * H * 2 - (size_t)F * H * 2);
    size_t hsz = align256((size_t)N * H * 2);
    char* zreg = hreg + hsz;
    unsigned* zs_u = (unsigned*)zreg;
    size_t zsz = align256((size_t)(N + 1) * PSU * 4);
    float* dinv = (float*)(zreg + zsz);
    int* rowbeg = (int*)(dinv + N);
    int* degp = rowbeg + N;
    int* bcntg = degp + N;
    int* esrc = bcntg + 256;

    const int nb_bin = (E + EPB - 1) / EPB;     // 391

    k_init<<<1 + F * H / 256, 256, 0, stream>>>(bcntg, W1, W1f,
                                                (unsigned*)(y + (size_t)N * H),
                                                zs_u + (size_t)N * PSU);
    k_bin<<<nb_bin, 256, 0, stream>>>(src, dst, bcntg, ebuf, E);
    k_bsort<<<NBUK, 256, 0, stream>>>(ebuf, bcntg, rowbeg, degp, dinv, esrc, N);
    k_gemm1<<<(N + 63) / 64, 256, 0, stream>>>(x, W1f, dinv, y, N);
    k_gather1z<<<(N + 31) / 32, 256, 0, stream>>>((const uint4*)y, rowbeg, degp,
                                                  esrc, dinv, b1, W2, zs_u, N);
    k_gather2<<<(N + 63) / 64, 256, 0, stream>>>(zs_u, rowbeg, degp, esrc,
                                                 dinv, b2, out, N);
}